// Round 5
// baseline (403.972 us; speedup 1.0000x reference)
//
#include <hip/hip_runtime.h>
#include <math.h>

// Fused HQCNN, round 10: wave-local dataflow (conv1 barrier removed) +
// depth-1 conv1 row pipeline + setprio on MFMA phases.
// - conv1: wave wv computes samples 4wv..4wv+3 (192 items = exactly 3/lane,
//   same balance as block-wide) -> conv2 consumes the SAME samples, so the
//   conv1->conv2 __syncthreads becomes a wave-local s_waitcnt lgkmcnt(0).
// - conv1 inner loop restructured to a rolling 2-row register window P[2][5]:
//   row u+1 loads issue before row u's 50 pk_fma -> VMEM latency overlapped
//   (old code: load-wait-compute per row, zero prefetch depth, VGPR=32).
// - conv2/fc1 MFMA clusters wrapped in s_setprio(1)/(0): waves run phase-
//   diverse (no barrier lockstep), scheduler can favor MFMA-issuing waves.
// - everything else as round 9: 16 samples/block, LDS overlay (pooled conv2
//   output written back into p1u), k'-permuted fc1, wave-0 tail, 8 blk/CU.

typedef float v2f __attribute__((ext_vector_type(2)));
typedef float f32x4 __attribute__((ext_vector_type(4)));
typedef short bf16x8 __attribute__((ext_vector_type(8)));
typedef unsigned int u32x4 __attribute__((ext_vector_type(4)));

union B8 { unsigned int u[4]; bf16x8 v; };

static __device__ __forceinline__ v2f vmax2(v2f a, v2f b) {
    return __builtin_elementwise_max(a, b);
}

// acc = w * splat(x.word) + acc ; w wave-uniform (SGPR pair), x v2f.
#define PK_FMA_W0(acc, w, xp) \
    asm("v_pk_fma_f32 %0, %1, %2, %0 op_sel:[0,0,0] op_sel_hi:[1,0,1]" \
        : "+v"(acc) : "s"(w), "v"(xp))
#define PK_FMA_W1(acc, w, xp) \
    asm("v_pk_fma_f32 %0, %1, %2, %0 op_sel:[0,1,0] op_sel_hi:[1,1,1]" \
        : "+v"(acc) : "s"(w), "v"(xp))

#define MFMA16(a, b, c) __builtin_amdgcn_mfma_f32_16x16x32_bf16(a, b, c, 0, 0, 0)

// byte selectors for v_perm_b32(hiSrc, loSrc, sel)
#define SEL_HI 0x07060302u   // take high16 of each source dword
#define SEL_LO 0x05040100u   // take low16 of each source dword

// pack float -> [hi-bf16 | lo-bf16] dword (truncation split)
static __device__ __forceinline__ unsigned int pack1(float v) {
    unsigned int hi = __float_as_uint(v) & 0xFFFF0000u;
    float lo = v - __uint_as_float(hi);
    return hi | (__float_as_uint(lo) >> 16);
}

// ws layout (ushort units)
#define A2_HI 0
#define A2_LO 1536
#define A1_HI 3072
#define A1_LO (3072 + 16384)
// total 35840 ushorts = 71680 B

#define P1_S 300   // dwords per sample: 288 data (2 ch x 144) + 8 zero pad
                   // cols 0..255 are overlaid with pooled conv2 output (k'-major)

__global__ __launch_bounds__(256)
void hqcnn_prep(const float* __restrict__ w2, const float* __restrict__ fw1,
                unsigned short* __restrict__ ws) {
    int t = blockIdx.x * 256 + threadIdx.x;
    if (blockIdx.x == 0) {
        // conv2 B-frags, frag-lane order: ws[cc*512 + lane*8 + j] holds
        // B[k=(lane>>4)*8+j][n=lane&15] ; k-group (cc*4+q) = row ch*5+u, j = v
        for (int e = threadIdx.x; e < 1536; e += 256) {
            int cc = e >> 9, r = e & 511;
            int lid = r >> 3, j = r & 7;
            int nn = lid & 15, qq = lid >> 4;
            int row = cc * 4 + qq;
            int ch = (row >= 5) ? 1 : 0;
            int u = row - 5 * ch;
            float val = (row < 10 && j < 5) ? w2[nn * 50 + ch * 25 + u * 5 + j] : 0.f;
            unsigned int uu = __float_as_uint(val);
            float lo = val - __uint_as_float(uu & 0xFFFF0000u);
            ws[A2_HI + e] = (unsigned short)(uu >> 16);
            ws[A2_LO + e] = (unsigned short)(__float_as_uint(lo) >> 16);
        }
    }
    // fc1 A with K permuted: k' = s16*16 + oc  <->  orig k = oc*16 + s16
    for (int e = t; e < 16384; e += gridDim.x * 256) {
        int m = e >> 8, kp = e & 255;
        int oc = kp & 15, s16 = kp >> 4;
        float val = fw1[m * 256 + oc * 16 + s16];
        unsigned int u = __float_as_uint(val);
        float lo = val - __uint_as_float(u & 0xFFFF0000u);
        ws[A1_HI + e] = (unsigned short)(u >> 16);
        ws[A1_LO + e] = (unsigned short)(__float_as_uint(lo) >> 16);
    }
}

__global__ __launch_bounds__(256, 8)
void hqcnn_fused(const float* __restrict__ x,    // (B,1,28,28)
                 const float* __restrict__ w1,   // (2,1,5,5)
                 const float* __restrict__ b1,   // (2,)
                 const float* __restrict__ b2,   // (16,)
                 const float* __restrict__ fb1,  // (64,)
                 const float* __restrict__ fw2,  // (2,64)
                 const float* __restrict__ fb2,  // (2,)
                 const float* __restrict__ fw3,  // (1,1)
                 const float* __restrict__ fb3,  // (1,)
                 const float* __restrict__ qp,   // (8,)
                 const unsigned short* __restrict__ ws,
                 float* __restrict__ out)        // (B,2)
{
    __shared__ __align__(16) unsigned int p1u[16 * P1_S];  // 19200 B, packed hi|lo
    __shared__ __align__(16) float zbuf[4 * 32];           //   512 B

    const int t = threadIdx.x;
    const int wv = t >> 6;
    const int lane = t & 63;
    const int n = lane & 15;
    const int q = lane >> 4;
    const long base = (long)blockIdx.x * 16;

    // zero own wave's samples' pad cols 288..295 (read by conv2 dead k-groups)
    if (lane < 32)
        p1u[(4 * wv + (lane >> 3)) * P1_S + 288 + (lane & 7)] = 0u;

    // ---- conv1 + relu + pool: WAVE-LOCAL fp32 pk_fma, 3 items/lane,
    //      depth-1 row prefetch window ----
    {
        v2f w1p[25];
        #pragma unroll
        for (int k = 0; k < 25; ++k)
            w1p[k] = (v2f){w1[k], w1[25 + k]};          // wave-uniform -> SGPR pairs
        const v2f bias1 = (v2f){b1[0], b1[1]};

        #pragma unroll
        for (int it = 0; it < 3; ++it) {
            int idx = it * 64 + lane;                    // [0,192) within wave
            int sl = idx / 48;                           // local sample 0..3
            int r = idx - sl * 48;
            int i = r >> 2, jh = r & 3;
            const int s = 4 * wv + sl;                   // wave-exclusive sample
            const float* xrow = x + (base + s) * 784 + 6 * jh;
            v2f acc[12];
            #pragma unroll
            for (int qq = 0; qq < 12; ++qq) acc[qq] = (v2f){0.f, 0.f};
            v2f P[2][5];
            {
                const v2f* xp = (const v2f*)(xrow + (2 * i) * 28);
                #pragma unroll
                for (int v5 = 0; v5 < 5; ++v5) P[0][v5] = xp[v5];
            }
            #pragma unroll
            for (int u = 0; u < 6; ++u) {
                if (u < 5) {                             // prefetch row u+1
                    const v2f* xp = (const v2f*)(xrow + (2 * i + u + 1) * 28);
                    #pragma unroll
                    for (int v5 = 0; v5 < 5; ++v5) P[(u + 1) & 1][v5] = xp[v5];
                }
                #pragma unroll
                for (int a = 0; a < 2; ++a) {
                    if (a <= u && (u - a) <= 4) {
                        const int wu = u - a;
                        #pragma unroll
                        for (int v = 0; v < 5; ++v) {
                            #pragma unroll
                            for (int j = 0; j < 6; ++j) {
                                const int e = j + v;
                                if (e & 1) { PK_FMA_W1(acc[a * 6 + j], w1p[wu * 5 + v], P[u & 1][e >> 1]); }
                                else       { PK_FMA_W0(acc[a * 6 + j], w1p[wu * 5 + v], P[u & 1][e >> 1]); }
                            }
                        }
                    }
                }
            }
            #pragma unroll
            for (int m = 0; m < 3; ++m) {
                v2f mx = vmax2(vmax2(acc[2 * m], acc[2 * m + 1]),
                               vmax2(acc[6 + 2 * m], acc[7 + 2 * m]));
                mx = mx + bias1;
                mx = vmax2(mx, (v2f){0.f, 0.f});
                int pc = 3 * jh + m;
                int off = s * P1_S + i * 12 + pc;
                p1u[off] = pack1(mx.x);            // channel 0 plane
                p1u[off + 144] = pack1(mx.y);      // channel 1 plane
            }
        }
    }
    // wave-local producer->consumer fence (conv2 reads only own wave's samples)
    asm volatile("s_waitcnt lgkmcnt(0)" ::: "memory");

    // ---- conv2 + relu + pool: transposed split-bf16 MFMA, reg pooling,
    //      pooled output written back INTO p1u[smp][0..255] (k' = s16*16+oc) ----
    {
        const bf16x8* B2h = (const bf16x8*)(ws + A2_HI);
        const bf16x8* B2l = (const bf16x8*)(ws + A2_LO);
        bf16x8 b_h[3], b_l[3];
        #pragma unroll
        for (int cc = 0; cc < 3; ++cc) {
            b_h[cc] = B2h[cc * 64 + lane];
            b_l[cc] = B2l[cc * 64 + lane];
        }
        // A side: lane holds A[m = lane&15][k = q*8+j].
        //   m = quad*4 + di*2 + dj : conv_i = 2*tt+di, conv_j = 2*quad+dj
        //   k-group (cc*4+q) = kernel row ch*5+u, j = v  (5 contiguous dwords)
        const int quad = n >> 2;
        const int di = (n >> 1) & 1;
        const int dj = n & 1;
        const int scol = 2 * quad + dj;
        int chu[3];
        #pragma unroll
        for (int cc = 0; cc < 3; ++cc) {
            int row = cc * 4 + q;
            int ch = (row >= 5) ? 1 : 0;
            int u = row - 5 * ch;
            chu[cc] = (row < 10) ? (ch * 144 + u * 12) : -1;
        }
        const float bias = b2[n];           // oc = n

        for (int sp = 0; sp < 4; ++sp) {
            const int smp = 4 * wv + sp;    // wave-exclusive sample rows
            const int sbase = smp * P1_S;
            const int zaddr = sbase + 288;  // zeroed pad
            float pvv[4];
            __builtin_amdgcn_s_setprio(1);
            #pragma unroll
            for (int tt = 0; tt < 4; ++tt) {
                int pbase = sbase + (2 * tt + di) * 12 + scol;
                f32x4 acc = {0.f, 0.f, 0.f, 0.f};
                f32x4 acc2 = {0.f, 0.f, 0.f, 0.f};
                #pragma unroll
                for (int cc = 0; cc < 3; ++cc) {
                    int a = (chu[cc] >= 0) ? (pbase + chu[cc]) : zaddr;
                    unsigned int e0 = p1u[a],     e1 = p1u[a + 1], e2 = p1u[a + 2],
                                 e3 = p1u[a + 3], e4 = p1u[a + 4];
                    B8 AH, AL;
                    AH.u[0] = __builtin_amdgcn_perm(e1, e0, SEL_HI);
                    AH.u[1] = __builtin_amdgcn_perm(e3, e2, SEL_HI);
                    AH.u[2] = e4 >> 16;
                    AH.u[3] = 0u;
                    AL.u[0] = __builtin_amdgcn_perm(e1, e0, SEL_LO);
                    AL.u[1] = __builtin_amdgcn_perm(e3, e2, SEL_LO);
                    AL.u[2] = e4 & 0xFFFFu;
                    AL.u[3] = 0u;
                    acc  = MFMA16(AH.v, b_h[cc], acc);
                    acc2 = MFMA16(AL.v, b_h[cc], acc2);
                    acc  = MFMA16(AH.v, b_l[cc], acc);
                }
                acc = acc + acc2;
                // D row = q*4 + r : pool quad q, member r; col = n = oc.
                float pv = fmaxf(fmaxf(acc[0], acc[1]), fmaxf(acc[2], acc[3]));
                pvv[tt] = fmaxf(pv + bias, 0.f);
            }
            __builtin_amdgcn_s_setprio(0);
            // overlay writeback: col = tt*64 + lane = (tt*4+q)*16 + n = s16*16+oc.
            // Data-dependent on all reads of this sample -> naturally ordered.
            #pragma unroll
            for (int tt = 0; tt < 4; ++tt)
                p1u[sbase + tt * 64 + lane] = pack1(pvv[tt]);
        }
    }
    __syncthreads();

    // ---- fc1 (split-bf16 MFMA, M=64, K=256, N=16 samples) + fc2 partials ----
    {
        const bf16x8* A1h = (const bf16x8*)(ws + A1_HI);
        const bf16x8* A1l = (const bf16x8*)(ws + A1_LO);
        const int abase = (wv * 16 + n) * 32 + q;    // A row m = wv*16+n
        f32x4 acc = {0.f, 0.f, 0.f, 0.f};
        f32x4 acc2 = {0.f, 0.f, 0.f, 0.f};
        __builtin_amdgcn_s_setprio(1);
        #pragma unroll
        for (int kk = 0; kk < 8; ++kk) {
            bf16x8 ah = A1h[abase + kk * 4];
            bf16x8 al = A1l[abase + kk * 4];
            // B[k'=kk*32+q*8+j][n] from overlaid p1u row n, cols 0..255
            const u32x4* hp = (const u32x4*)(p1u + n * P1_S + kk * 32 + q * 8);
            u32x4 d0 = hp[0], d1 = hp[1];
            B8 BH, BL;
            BH.u[0] = __builtin_amdgcn_perm(d0.y, d0.x, SEL_HI);
            BH.u[1] = __builtin_amdgcn_perm(d0.w, d0.z, SEL_HI);
            BH.u[2] = __builtin_amdgcn_perm(d1.y, d1.x, SEL_HI);
            BH.u[3] = __builtin_amdgcn_perm(d1.w, d1.z, SEL_HI);
            BL.u[0] = __builtin_amdgcn_perm(d0.y, d0.x, SEL_LO);
            BL.u[1] = __builtin_amdgcn_perm(d0.w, d0.z, SEL_LO);
            BL.u[2] = __builtin_amdgcn_perm(d1.y, d1.x, SEL_LO);
            BL.u[3] = __builtin_amdgcn_perm(d1.w, d1.z, SEL_LO);
            acc  = MFMA16(ah, BH.v, acc);
            acc2 = MFMA16(ah, BL.v, acc2);
            acc  = MFMA16(al, BH.v, acc);
        }
        __builtin_amdgcn_s_setprio(0);
        acc = acc + acc2;
        // D rows m = wv*16 + q*4 + r, cols n = sample
        f32x4 fb4 = *(const f32x4*)(fb1 + wv * 16 + q * 4);
        f32x4 w20 = *(const f32x4*)(fw2 + wv * 16 + q * 4);
        f32x4 w21 = *(const f32x4*)(fw2 + 64 + wv * 16 + q * 4);
        float p0 = 0.f, p1v = 0.f;
        #pragma unroll
        for (int r = 0; r < 4; ++r) {
            float a = fmaxf(acc[r] + fb4[r], 0.f);
            p0  = fmaf(a, w20[r], p0);
            p1v = fmaf(a, w21[r], p1v);
        }
        p0  += __shfl_xor(p0, 16, 64);  p0  += __shfl_xor(p0, 32, 64);
        p1v += __shfl_xor(p1v, 16, 64); p1v += __shfl_xor(p1v, 32, 64);
        if (q == 0) {
            zbuf[wv * 32 + n * 2]     = p0;
            zbuf[wv * 32 + n * 2 + 1] = p1v;
        }
    }
    __syncthreads();
    if (wv != 0) return;          // tail on wave 0 only

    // ---- fc2 sum + quantum + fc3 + log_softmax (wave 0, 16 samples) ----
    {
        int s = lane & 15;
        float x0 = fb2[0] + zbuf[s * 2]     + zbuf[32 + s * 2]
                          + zbuf[64 + s * 2] + zbuf[96 + s * 2];
        float x1 = fb2[1] + zbuf[s * 2 + 1] + zbuf[32 + s * 2 + 1]
                          + zbuf[64 + s * 2 + 1] + zbuf[96 + s * 2 + 1];

        float sr[4], si[4];
        {
            float th0 = -x0 - x1, th1 = -x0 + x1, th2 = x0 - x1, th3 = x0 + x1;
            sr[0] = 0.5f * __cosf(th0); si[0] = 0.5f * __sinf(th0);
            sr[1] = 0.5f * __cosf(th1); si[1] = 0.5f * __sinf(th1);
            sr[2] = 0.5f * __cosf(th2); si[2] = 0.5f * __sinf(th2);
            sr[3] = 0.5f * __cosf(th3); si[3] = 0.5f * __sinf(th3);
        }
        {
            float tr = sr[2]; sr[2] = sr[3]; sr[3] = tr;
            float ti = si[2]; si[2] = si[3]; si[3] = ti;
            float ang = ((float)M_PI - x0) * ((float)M_PI - x1);
            float ca = __cosf(ang), sa = __sinf(ang);
            float r, im;
            r = sr[0]; im = si[0]; sr[0] = r*ca + im*sa; si[0] = im*ca - r*sa;
            r = sr[2]; im = si[2]; sr[2] = r*ca + im*sa; si[2] = im*ca - r*sa;
            r = sr[1]; im = si[1]; sr[1] = r*ca - im*sa; si[1] = im*ca + r*sa;
            r = sr[3]; im = si[3]; sr[3] = r*ca - im*sa; si[3] = im*ca + r*sa;
            tr = sr[2]; sr[2] = sr[3]; sr[3] = tr;
            ti = si[2]; si[2] = si[3]; si[3] = ti;
        }
        float cp[8], sp[8];
        #pragma unroll
        for (int g = 0; g < 8; ++g) { float qv = qp[g]; cp[g] = __cosf(qv); sp[g] = __sinf(qv); }

        #define QRY0(cc, ss) { \
            float a0r=sr[0], a0i=si[0], a1r=sr[2], a1i=si[2]; \
            sr[0]=cc*a0r-ss*a1r; si[0]=cc*a0i-ss*a1i; \
            sr[2]=ss*a0r+cc*a1r; si[2]=ss*a0i+cc*a1i; \
            float b0r=sr[1], b0i=si[1], b1r=sr[3], b1i=si[3]; \
            sr[1]=cc*b0r-ss*b1r; si[1]=cc*b0i-ss*b1i; \
            sr[3]=ss*b0r+cc*b1r; si[3]=ss*b0i+cc*b1i; }
        #define QRY1(cc, ss) { \
            float a0r=sr[0], a0i=si[0], a1r=sr[1], a1i=si[1]; \
            sr[0]=cc*a0r-ss*a1r; si[0]=cc*a0i-ss*a1i; \
            sr[1]=ss*a0r+cc*a1r; si[1]=ss*a0i+cc*a1i; \
            float b0r=sr[2], b0i=si[2], b1r=sr[3], b1i=si[3]; \
            sr[2]=cc*b0r-ss*b1r; si[2]=cc*b0i-ss*b1i; \
            sr[3]=ss*b0r+cc*b1r; si[3]=ss*b0i+cc*b1i; }
        #define QSWAP(i_, j_) { float tr=sr[i_]; sr[i_]=sr[j_]; sr[j_]=tr; \
                                float ti=si[i_]; si[i_]=si[j_]; si[j_]=ti; }

        QRY0(cp[0], sp[0]);
        QRY1(cp[1], sp[1]);
        QSWAP(2, 3);                 // cnot01
        QRY0(cp[2], sp[2]);
        QRY1(cp[3], sp[3]);
        QSWAP(1, 3);                 // cnot10
        QRY0(cp[4], sp[4]);
        QRY1(cp[5], sp[5]);
        QSWAP(2, 3);                 // cnot01
        QRY0(cp[6], sp[6]);
        QRY1(cp[7], sp[7]);

        float qv = (sr[0]*sr[0] + si[0]*si[0])
                 - (sr[1]*sr[1] + si[1]*si[1])
                 - (sr[2]*sr[2] + si[2]*si[2])
                 + (sr[3]*sr[3] + si[3]*si[3]);
        float y = fmaf(qv, fw3[0], fb3[0]);
        float l0 = y, l1 = 1.0f - y;
        float m = fmaxf(l0, l1);
        float lse = m + __logf(__expf(l0 - m) + __expf(l1 - m));
        if (lane < 32) {
            int comp = lane >> 4;
            out[(base + s) * 2 + comp] = comp ? (l1 - lse) : (l0 - lse);
        }
        #undef QRY0
        #undef QRY1
        #undef QSWAP
    }
}

extern "C" void kernel_launch(void* const* d_in, const int* in_sizes, int n_in,
                              void* d_out, int out_size, void* d_ws, size_t ws_size,
                              hipStream_t stream) {
    const float* x   = (const float*)d_in[0];
    const float* w1  = (const float*)d_in[1];
    const float* b1  = (const float*)d_in[2];
    const float* w2  = (const float*)d_in[3];
    const float* b2  = (const float*)d_in[4];
    const float* fw1 = (const float*)d_in[5];
    const float* fb1 = (const float*)d_in[6];
    const float* fw2 = (const float*)d_in[7];
    const float* fb2 = (const float*)d_in[8];
    const float* fw3 = (const float*)d_in[9];
    const float* fb3 = (const float*)d_in[10];
    const float* qp  = (const float*)d_in[11];
    float* outp = (float*)d_out;
    unsigned short* wsp = (unsigned short*)d_ws;

    hipLaunchKernelGGL(hqcnn_prep, dim3(64), dim3(256), 0, stream, w2, fw1, wsp);

    int B = in_sizes[0] / 784;     // 65536
    int nblk = B / 16;             // 16 samples per block
    hipLaunchKernelGGL(hqcnn_fused, dim3(nblk), dim3(256), 0, stream,
                       x, w1, b1, b2, fb1, fw2, fb2, fw3, fb3, qp, wsp, outp);
}

// Round 6
// 396.923 us; speedup vs baseline: 1.0178x; 1.0178x over previous
//
#include <hip/hip_runtime.h>
#include <math.h>

// Fused HQCNN, round 11: round-9 conv1 body (no prefetch window — round 10's
// P[2][5] window caused scratch spill: WRITE_SIZE 512KB->53.7MB) + wave-local
// dataflow + setprio on MFMA phases.
// - conv1: wave wv computes samples 4wv..4wv+3 (192 items = exactly 3/lane),
//   inner loop EXACTLY round 9's (per-row P[5], loads consumed immediately).
//   conv2 consumes the same wave's samples -> conv1->conv2 barrier is a
//   wave-local s_waitcnt lgkmcnt(0), no block convoy.
// - conv2/fc1 MFMA clusters in s_setprio(1)/(0) (waves phase-diverse here).
// - rest as round 9: 16 samples/block, LDS overlay (pooled conv2 out written
//   back into p1u), k'-permuted fc1, wave-0 tail, 8 blocks/CU.

typedef float v2f __attribute__((ext_vector_type(2)));
typedef float f32x4 __attribute__((ext_vector_type(4)));
typedef short bf16x8 __attribute__((ext_vector_type(8)));
typedef unsigned int u32x4 __attribute__((ext_vector_type(4)));

union B8 { unsigned int u[4]; bf16x8 v; };

static __device__ __forceinline__ v2f vmax2(v2f a, v2f b) {
    return __builtin_elementwise_max(a, b);
}

// acc = w * splat(x.word) + acc ; w wave-uniform (SGPR pair), x v2f.
#define PK_FMA_W0(acc, w, xp) \
    asm("v_pk_fma_f32 %0, %1, %2, %0 op_sel:[0,0,0] op_sel_hi:[1,0,1]" \
        : "+v"(acc) : "s"(w), "v"(xp))
#define PK_FMA_W1(acc, w, xp) \
    asm("v_pk_fma_f32 %0, %1, %2, %0 op_sel:[0,1,0] op_sel_hi:[1,1,1]" \
        : "+v"(acc) : "s"(w), "v"(xp))

#define MFMA16(a, b, c) __builtin_amdgcn_mfma_f32_16x16x32_bf16(a, b, c, 0, 0, 0)

// byte selectors for v_perm_b32(hiSrc, loSrc, sel)
#define SEL_HI 0x07060302u   // take high16 of each source dword
#define SEL_LO 0x05040100u   // take low16 of each source dword

// pack float -> [hi-bf16 | lo-bf16] dword (truncation split)
static __device__ __forceinline__ unsigned int pack1(float v) {
    unsigned int hi = __float_as_uint(v) & 0xFFFF0000u;
    float lo = v - __uint_as_float(hi);
    return hi | (__float_as_uint(lo) >> 16);
}

// ws layout (ushort units)
#define A2_HI 0
#define A2_LO 1536
#define A1_HI 3072
#define A1_LO (3072 + 16384)
// total 35840 ushorts = 71680 B

#define P1_S 300   // dwords per sample: 288 data (2 ch x 144) + 8 zero pad
                   // cols 0..255 are overlaid with pooled conv2 output (k'-major)

__global__ __launch_bounds__(256)
void hqcnn_prep(const float* __restrict__ w2, const float* __restrict__ fw1,
                unsigned short* __restrict__ ws) {
    int t = blockIdx.x * 256 + threadIdx.x;
    if (blockIdx.x == 0) {
        // conv2 B-frags, frag-lane order: ws[cc*512 + lane*8 + j] holds
        // B[k=(lane>>4)*8+j][n=lane&15] ; k-group (cc*4+q) = row ch*5+u, j = v
        for (int e = threadIdx.x; e < 1536; e += 256) {
            int cc = e >> 9, r = e & 511;
            int lid = r >> 3, j = r & 7;
            int nn = lid & 15, qq = lid >> 4;
            int row = cc * 4 + qq;
            int ch = (row >= 5) ? 1 : 0;
            int u = row - 5 * ch;
            float val = (row < 10 && j < 5) ? w2[nn * 50 + ch * 25 + u * 5 + j] : 0.f;
            unsigned int uu = __float_as_uint(val);
            float lo = val - __uint_as_float(uu & 0xFFFF0000u);
            ws[A2_HI + e] = (unsigned short)(uu >> 16);
            ws[A2_LO + e] = (unsigned short)(__float_as_uint(lo) >> 16);
        }
    }
    // fc1 A with K permuted: k' = s16*16 + oc  <->  orig k = oc*16 + s16
    for (int e = t; e < 16384; e += gridDim.x * 256) {
        int m = e >> 8, kp = e & 255;
        int oc = kp & 15, s16 = kp >> 4;
        float val = fw1[m * 256 + oc * 16 + s16];
        unsigned int u = __float_as_uint(val);
        float lo = val - __uint_as_float(u & 0xFFFF0000u);
        ws[A1_HI + e] = (unsigned short)(u >> 16);
        ws[A1_LO + e] = (unsigned short)(__float_as_uint(lo) >> 16);
    }
}

__global__ __launch_bounds__(256, 8)
void hqcnn_fused(const float* __restrict__ x,    // (B,1,28,28)
                 const float* __restrict__ w1,   // (2,1,5,5)
                 const float* __restrict__ b1,   // (2,)
                 const float* __restrict__ b2,   // (16,)
                 const float* __restrict__ fb1,  // (64,)
                 const float* __restrict__ fw2,  // (2,64)
                 const float* __restrict__ fb2,  // (2,)
                 const float* __restrict__ fw3,  // (1,1)
                 const float* __restrict__ fb3,  // (1,)
                 const float* __restrict__ qp,   // (8,)
                 const unsigned short* __restrict__ ws,
                 float* __restrict__ out)        // (B,2)
{
    __shared__ __align__(16) unsigned int p1u[16 * P1_S];  // 19200 B, packed hi|lo
    __shared__ __align__(16) float zbuf[4 * 32];           //   512 B

    const int t = threadIdx.x;
    const int wv = t >> 6;
    const int lane = t & 63;
    const int n = lane & 15;
    const int q = lane >> 4;
    const long base = (long)blockIdx.x * 16;

    // zero own wave's samples' pad cols 288..295 (read by conv2 dead k-groups)
    if (lane < 32)
        p1u[(4 * wv + (lane >> 3)) * P1_S + 288 + (lane & 7)] = 0u;

    // ---- conv1 + relu + pool: WAVE-LOCAL fp32 pk_fma, 3 items/lane,
    //      round-9 inner body (per-row loads, consumed immediately) ----
    {
        v2f w1p[25];
        #pragma unroll
        for (int k = 0; k < 25; ++k)
            w1p[k] = (v2f){w1[k], w1[25 + k]};          // wave-uniform -> SGPR pairs
        const v2f bias1 = (v2f){b1[0], b1[1]};

        #pragma unroll
        for (int it = 0; it < 3; ++it) {
            int idx = it * 64 + lane;                    // [0,192) within wave
            int sl = idx / 48;                           // local sample 0..3
            int r = idx - sl * 48;
            int i = r >> 2, jh = r & 3;
            const int s = 4 * wv + sl;                   // wave-exclusive sample
            const float* xrow = x + (base + s) * 784;
            v2f acc[12];
            #pragma unroll
            for (int qq = 0; qq < 12; ++qq) acc[qq] = (v2f){0.f, 0.f};
            #pragma unroll
            for (int u = 0; u < 6; ++u) {
                const v2f* xp = (const v2f*)(xrow + (2 * i + u) * 28 + 6 * jh);
                v2f P[5] = { xp[0], xp[1], xp[2], xp[3], xp[4] };
                #pragma unroll
                for (int a = 0; a < 2; ++a) {
                    if (a <= u && (u - a) <= 4) {
                        const int wu = u - a;
                        #pragma unroll
                        for (int v = 0; v < 5; ++v) {
                            #pragma unroll
                            for (int j = 0; j < 6; ++j) {
                                const int e = j + v;
                                if (e & 1) { PK_FMA_W1(acc[a * 6 + j], w1p[wu * 5 + v], P[e >> 1]); }
                                else       { PK_FMA_W0(acc[a * 6 + j], w1p[wu * 5 + v], P[e >> 1]); }
                            }
                        }
                    }
                }
            }
            #pragma unroll
            for (int m = 0; m < 3; ++m) {
                v2f mx = vmax2(vmax2(acc[2 * m], acc[2 * m + 1]),
                               vmax2(acc[6 + 2 * m], acc[7 + 2 * m]));
                mx = mx + bias1;
                mx = vmax2(mx, (v2f){0.f, 0.f});
                int pc = 3 * jh + m;
                int off = s * P1_S + i * 12 + pc;
                p1u[off] = pack1(mx.x);            // channel 0 plane
                p1u[off + 144] = pack1(mx.y);      // channel 1 plane
            }
        }
    }
    // wave-local producer->consumer fence (conv2 reads only own wave's samples)
    asm volatile("s_waitcnt lgkmcnt(0)" ::: "memory");

    // ---- conv2 + relu + pool: transposed split-bf16 MFMA, reg pooling,
    //      pooled output written back INTO p1u[smp][0..255] (k' = s16*16+oc) ----
    {
        const bf16x8* B2h = (const bf16x8*)(ws + A2_HI);
        const bf16x8* B2l = (const bf16x8*)(ws + A2_LO);
        bf16x8 b_h[3], b_l[3];
        #pragma unroll
        for (int cc = 0; cc < 3; ++cc) {
            b_h[cc] = B2h[cc * 64 + lane];
            b_l[cc] = B2l[cc * 64 + lane];
        }
        // A side: lane holds A[m = lane&15][k = q*8+j].
        //   m = quad*4 + di*2 + dj : conv_i = 2*tt+di, conv_j = 2*quad+dj
        //   k-group (cc*4+q) = kernel row ch*5+u, j = v  (5 contiguous dwords)
        const int quad = n >> 2;
        const int di = (n >> 1) & 1;
        const int dj = n & 1;
        const int scol = 2 * quad + dj;
        int chu[3];
        #pragma unroll
        for (int cc = 0; cc < 3; ++cc) {
            int row = cc * 4 + q;
            int ch = (row >= 5) ? 1 : 0;
            int u = row - 5 * ch;
            chu[cc] = (row < 10) ? (ch * 144 + u * 12) : -1;
        }
        const float bias = b2[n];           // oc = n

        for (int sp = 0; sp < 4; ++sp) {
            const int smp = 4 * wv + sp;    // wave-exclusive sample rows
            const int sbase = smp * P1_S;
            const int zaddr = sbase + 288;  // zeroed pad
            float pvv[4];
            __builtin_amdgcn_s_setprio(1);
            #pragma unroll
            for (int tt = 0; tt < 4; ++tt) {
                int pbase = sbase + (2 * tt + di) * 12 + scol;
                f32x4 acc = {0.f, 0.f, 0.f, 0.f};
                f32x4 acc2 = {0.f, 0.f, 0.f, 0.f};
                #pragma unroll
                for (int cc = 0; cc < 3; ++cc) {
                    int a = (chu[cc] >= 0) ? (pbase + chu[cc]) : zaddr;
                    unsigned int e0 = p1u[a],     e1 = p1u[a + 1], e2 = p1u[a + 2],
                                 e3 = p1u[a + 3], e4 = p1u[a + 4];
                    B8 AH, AL;
                    AH.u[0] = __builtin_amdgcn_perm(e1, e0, SEL_HI);
                    AH.u[1] = __builtin_amdgcn_perm(e3, e2, SEL_HI);
                    AH.u[2] = e4 >> 16;
                    AH.u[3] = 0u;
                    AL.u[0] = __builtin_amdgcn_perm(e1, e0, SEL_LO);
                    AL.u[1] = __builtin_amdgcn_perm(e3, e2, SEL_LO);
                    AL.u[2] = e4 & 0xFFFFu;
                    AL.u[3] = 0u;
                    acc  = MFMA16(AH.v, b_h[cc], acc);
                    acc2 = MFMA16(AL.v, b_h[cc], acc2);
                    acc  = MFMA16(AH.v, b_l[cc], acc);
                }
                acc = acc + acc2;
                // D row = q*4 + r : pool quad q, member r; col = n = oc.
                float pv = fmaxf(fmaxf(acc[0], acc[1]), fmaxf(acc[2], acc[3]));
                pvv[tt] = fmaxf(pv + bias, 0.f);
            }
            __builtin_amdgcn_s_setprio(0);
            // overlay writeback: col = tt*64 + lane = (tt*4+q)*16 + n = s16*16+oc.
            // Data-dependent on all reads of this sample -> naturally ordered.
            #pragma unroll
            for (int tt = 0; tt < 4; ++tt)
                p1u[sbase + tt * 64 + lane] = pack1(pvv[tt]);
        }
    }
    __syncthreads();

    // ---- fc1 (split-bf16 MFMA, M=64, K=256, N=16 samples) + fc2 partials ----
    {
        const bf16x8* A1h = (const bf16x8*)(ws + A1_HI);
        const bf16x8* A1l = (const bf16x8*)(ws + A1_LO);
        const int abase = (wv * 16 + n) * 32 + q;    // A row m = wv*16+n
        f32x4 acc = {0.f, 0.f, 0.f, 0.f};
        f32x4 acc2 = {0.f, 0.f, 0.f, 0.f};
        __builtin_amdgcn_s_setprio(1);
        #pragma unroll
        for (int kk = 0; kk < 8; ++kk) {
            bf16x8 ah = A1h[abase + kk * 4];
            bf16x8 al = A1l[abase + kk * 4];
            // B[k'=kk*32+q*8+j][n] from overlaid p1u row n, cols 0..255
            const u32x4* hp = (const u32x4*)(p1u + n * P1_S + kk * 32 + q * 8);
            u32x4 d0 = hp[0], d1 = hp[1];
            B8 BH, BL;
            BH.u[0] = __builtin_amdgcn_perm(d0.y, d0.x, SEL_HI);
            BH.u[1] = __builtin_amdgcn_perm(d0.w, d0.z, SEL_HI);
            BH.u[2] = __builtin_amdgcn_perm(d1.y, d1.x, SEL_HI);
            BH.u[3] = __builtin_amdgcn_perm(d1.w, d1.z, SEL_HI);
            BL.u[0] = __builtin_amdgcn_perm(d0.y, d0.x, SEL_LO);
            BL.u[1] = __builtin_amdgcn_perm(d0.w, d0.z, SEL_LO);
            BL.u[2] = __builtin_amdgcn_perm(d1.y, d1.x, SEL_LO);
            BL.u[3] = __builtin_amdgcn_perm(d1.w, d1.z, SEL_LO);
            acc  = MFMA16(ah, BH.v, acc);
            acc2 = MFMA16(ah, BL.v, acc2);
            acc  = MFMA16(al, BH.v, acc);
        }
        __builtin_amdgcn_s_setprio(0);
        acc = acc + acc2;
        // D rows m = wv*16 + q*4 + r, cols n = sample
        f32x4 fb4 = *(const f32x4*)(fb1 + wv * 16 + q * 4);
        f32x4 w20 = *(const f32x4*)(fw2 + wv * 16 + q * 4);
        f32x4 w21 = *(const f32x4*)(fw2 + 64 + wv * 16 + q * 4);
        float p0 = 0.f, p1v = 0.f;
        #pragma unroll
        for (int r = 0; r < 4; ++r) {
            float a = fmaxf(acc[r] + fb4[r], 0.f);
            p0  = fmaf(a, w20[r], p0);
            p1v = fmaf(a, w21[r], p1v);
        }
        p0  += __shfl_xor(p0, 16, 64);  p0  += __shfl_xor(p0, 32, 64);
        p1v += __shfl_xor(p1v, 16, 64); p1v += __shfl_xor(p1v, 32, 64);
        if (q == 0) {
            zbuf[wv * 32 + n * 2]     = p0;
            zbuf[wv * 32 + n * 2 + 1] = p1v;
        }
    }
    __syncthreads();
    if (wv != 0) return;          // tail on wave 0 only

    // ---- fc2 sum + quantum + fc3 + log_softmax (wave 0, 16 samples) ----
    {
        int s = lane & 15;
        float x0 = fb2[0] + zbuf[s * 2]     + zbuf[32 + s * 2]
                          + zbuf[64 + s * 2] + zbuf[96 + s * 2];
        float x1 = fb2[1] + zbuf[s * 2 + 1] + zbuf[32 + s * 2 + 1]
                          + zbuf[64 + s * 2 + 1] + zbuf[96 + s * 2 + 1];

        float sr[4], si[4];
        {
            float th0 = -x0 - x1, th1 = -x0 + x1, th2 = x0 - x1, th3 = x0 + x1;
            sr[0] = 0.5f * __cosf(th0); si[0] = 0.5f * __sinf(th0);
            sr[1] = 0.5f * __cosf(th1); si[1] = 0.5f * __sinf(th1);
            sr[2] = 0.5f * __cosf(th2); si[2] = 0.5f * __sinf(th2);
            sr[3] = 0.5f * __cosf(th3); si[3] = 0.5f * __sinf(th3);
        }
        {
            float tr = sr[2]; sr[2] = sr[3]; sr[3] = tr;
            float ti = si[2]; si[2] = si[3]; si[3] = ti;
            float ang = ((float)M_PI - x0) * ((float)M_PI - x1);
            float ca = __cosf(ang), sa = __sinf(ang);
            float r, im;
            r = sr[0]; im = si[0]; sr[0] = r*ca + im*sa; si[0] = im*ca - r*sa;
            r = sr[2]; im = si[2]; sr[2] = r*ca + im*sa; si[2] = im*ca - r*sa;
            r = sr[1]; im = si[1]; sr[1] = r*ca - im*sa; si[1] = im*ca + r*sa;
            r = sr[3]; im = si[3]; sr[3] = r*ca - im*sa; si[3] = im*ca + r*sa;
            tr = sr[2]; sr[2] = sr[3]; sr[3] = tr;
            ti = si[2]; si[2] = si[3]; si[3] = ti;
        }
        float cp[8], sp[8];
        #pragma unroll
        for (int g = 0; g < 8; ++g) { float qv = qp[g]; cp[g] = __cosf(qv); sp[g] = __sinf(qv); }

        #define QRY0(cc, ss) { \
            float a0r=sr[0], a0i=si[0], a1r=sr[2], a1i=si[2]; \
            sr[0]=cc*a0r-ss*a1r; si[0]=cc*a0i-ss*a1i; \
            sr[2]=ss*a0r+cc*a1r; si[2]=ss*a0i+cc*a1i; \
            float b0r=sr[1], b0i=si[1], b1r=sr[3], b1i=si[3]; \
            sr[1]=cc*b0r-ss*b1r; si[1]=cc*b0i-ss*b1i; \
            sr[3]=ss*b0r+cc*b1r; si[3]=ss*b0i+cc*b1i; }
        #define QRY1(cc, ss) { \
            float a0r=sr[0], a0i=si[0], a1r=sr[1], a1i=si[1]; \
            sr[0]=cc*a0r-ss*a1r; si[0]=cc*a0i-ss*a1i; \
            sr[1]=ss*a0r+cc*a1r; si[1]=ss*a0i+cc*a1i; \
            float b0r=sr[2], b0i=si[2], b1r=sr[3], b1i=si[3]; \
            sr[2]=cc*b0r-ss*b1r; si[2]=cc*b0i-ss*b1i; \
            sr[3]=ss*b0r+cc*b1r; si[3]=ss*b0i+cc*b1i; }
        #define QSWAP(i_, j_) { float tr=sr[i_]; sr[i_]=sr[j_]; sr[j_]=tr; \
                                float ti=si[i_]; si[i_]=si[j_]; si[j_]=ti; }

        QRY0(cp[0], sp[0]);
        QRY1(cp[1], sp[1]);
        QSWAP(2, 3);                 // cnot01
        QRY0(cp[2], sp[2]);
        QRY1(cp[3], sp[3]);
        QSWAP(1, 3);                 // cnot10
        QRY0(cp[4], sp[4]);
        QRY1(cp[5], sp[5]);
        QSWAP(2, 3);                 // cnot01
        QRY0(cp[6], sp[6]);
        QRY1(cp[7], sp[7]);

        float qv = (sr[0]*sr[0] + si[0]*si[0])
                 - (sr[1]*sr[1] + si[1]*si[1])
                 - (sr[2]*sr[2] + si[2]*si[2])
                 + (sr[3]*sr[3] + si[3]*si[3]);
        float y = fmaf(qv, fw3[0], fb3[0]);
        float l0 = y, l1 = 1.0f - y;
        float m = fmaxf(l0, l1);
        float lse = m + __logf(__expf(l0 - m) + __expf(l1 - m));
        if (lane < 32) {
            int comp = lane >> 4;
            out[(base + s) * 2 + comp] = comp ? (l1 - lse) : (l0 - lse);
        }
        #undef QRY0
        #undef QRY1
        #undef QSWAP
    }
}

extern "C" void kernel_launch(void* const* d_in, const int* in_sizes, int n_in,
                              void* d_out, int out_size, void* d_ws, size_t ws_size,
                              hipStream_t stream) {
    const float* x   = (const float*)d_in[0];
    const float* w1  = (const float*)d_in[1];
    const float* b1  = (const float*)d_in[2];
    const float* w2  = (const float*)d_in[3];
    const float* b2  = (const float*)d_in[4];
    const float* fw1 = (const float*)d_in[5];
    const float* fb1 = (const float*)d_in[6];
    const float* fw2 = (const float*)d_in[7];
    const float* fb2 = (const float*)d_in[8];
    const float* fw3 = (const float*)d_in[9];
    const float* fb3 = (const float*)d_in[10];
    const float* qp  = (const float*)d_in[11];
    float* outp = (float*)d_out;
    unsigned short* wsp = (unsigned short*)d_ws;

    hipLaunchKernelGGL(hqcnn_prep, dim3(64), dim3(256), 0, stream, w2, fw1, wsp);

    int B = in_sizes[0] / 784;     // 65536
    int nblk = B / 16;             // 16 samples per block
    hipLaunchKernelGGL(hqcnn_fused, dim3(nblk), dim3(256), 0, stream,
                       x, w1, b1, b2, fb1, fw2, fb2, fw3, fb3, qp, wsp, outp);
}

// Round 7
// 383.342 us; speedup vs baseline: 1.0538x; 1.0354x over previous
//
#include <hip/hip_runtime.h>
#include <math.h>

// Fused HQCNN, round 12: restore conv1->conv2 __syncthreads (rounds 10/11's
// wave-local fence fused scheduling regions -> live-range blowup past the
// 64-VGPR cap -> 41-54 MB scratch spill; barrier = region boundary, r9 had
// none) + hi/lo PLANE storage for conv2 output (fc1 B-frags become direct
// ds_read_b128, all 64 fc1 v_perm_b32 per thread eliminated).
// - conv1: wave-local mapping (3 items/lane), round-9 inner body.
// - conv2: transposed split-bf16 MFMA, reg pooling; pooled output written to
//   ushort planes inside the overlay: hi at u16 col k', lo at 256+k'.
// - fc1: B = two b128 reads (hi plane, lo plane) per kk; A prepped in d_ws.
// - setprio(1) around MFMA clusters; wave-0 tail; 16 samples/block; 8 blk/CU.

typedef float v2f __attribute__((ext_vector_type(2)));
typedef float f32x4 __attribute__((ext_vector_type(4)));
typedef short bf16x8 __attribute__((ext_vector_type(8)));

union B8 { unsigned int u[4]; bf16x8 v; };

static __device__ __forceinline__ v2f vmax2(v2f a, v2f b) {
    return __builtin_elementwise_max(a, b);
}

// acc = w * splat(x.word) + acc ; w wave-uniform (SGPR pair), x v2f.
#define PK_FMA_W0(acc, w, xp) \
    asm("v_pk_fma_f32 %0, %1, %2, %0 op_sel:[0,0,0] op_sel_hi:[1,0,1]" \
        : "+v"(acc) : "s"(w), "v"(xp))
#define PK_FMA_W1(acc, w, xp) \
    asm("v_pk_fma_f32 %0, %1, %2, %0 op_sel:[0,1,0] op_sel_hi:[1,1,1]" \
        : "+v"(acc) : "s"(w), "v"(xp))

#define MFMA16(a, b, c) __builtin_amdgcn_mfma_f32_16x16x32_bf16(a, b, c, 0, 0, 0)

// byte selectors for v_perm_b32(hiSrc, loSrc, sel)
#define SEL_HI 0x07060302u   // take high16 of each source dword
#define SEL_LO 0x05040100u   // take low16 of each source dword

// pack float -> [hi-bf16 | lo-bf16] dword (truncation split)
static __device__ __forceinline__ unsigned int pack1(float v) {
    unsigned int hi = __float_as_uint(v) & 0xFFFF0000u;
    float lo = v - __uint_as_float(hi);
    return hi | (__float_as_uint(lo) >> 16);
}

// ws layout (ushort units)
#define A2_HI 0
#define A2_LO 1536
#define A1_HI 3072
#define A1_LO (3072 + 16384)
// total 35840 ushorts = 71680 B

#define P1_S 300   // dwords per sample: 288 data (2 ch x 144) + 8 zero pad.
                   // After conv2: u16 cols 0..255 = hi plane, 256..511 = lo
                   // plane of the pooled output (k' = s16*16+oc).

__global__ __launch_bounds__(256)
void hqcnn_prep(const float* __restrict__ w2, const float* __restrict__ fw1,
                unsigned short* __restrict__ ws) {
    int t = blockIdx.x * 256 + threadIdx.x;
    if (blockIdx.x == 0) {
        // conv2 B-frags, frag-lane order: ws[cc*512 + lane*8 + j] holds
        // B[k=(lane>>4)*8+j][n=lane&15] ; k-group (cc*4+q) = row ch*5+u, j = v
        for (int e = threadIdx.x; e < 1536; e += 256) {
            int cc = e >> 9, r = e & 511;
            int lid = r >> 3, j = r & 7;
            int nn = lid & 15, qq = lid >> 4;
            int row = cc * 4 + qq;
            int ch = (row >= 5) ? 1 : 0;
            int u = row - 5 * ch;
            float val = (row < 10 && j < 5) ? w2[nn * 50 + ch * 25 + u * 5 + j] : 0.f;
            unsigned int uu = __float_as_uint(val);
            float lo = val - __uint_as_float(uu & 0xFFFF0000u);
            ws[A2_HI + e] = (unsigned short)(uu >> 16);
            ws[A2_LO + e] = (unsigned short)(__float_as_uint(lo) >> 16);
        }
    }
    // fc1 A with K permuted: k' = s16*16 + oc  <->  orig k = oc*16 + s16
    for (int e = t; e < 16384; e += gridDim.x * 256) {
        int m = e >> 8, kp = e & 255;
        int oc = kp & 15, s16 = kp >> 4;
        float val = fw1[m * 256 + oc * 16 + s16];
        unsigned int u = __float_as_uint(val);
        float lo = val - __uint_as_float(u & 0xFFFF0000u);
        ws[A1_HI + e] = (unsigned short)(u >> 16);
        ws[A1_LO + e] = (unsigned short)(__float_as_uint(lo) >> 16);
    }
}

__global__ __launch_bounds__(256, 8)
void hqcnn_fused(const float* __restrict__ x,    // (B,1,28,28)
                 const float* __restrict__ w1,   // (2,1,5,5)
                 const float* __restrict__ b1,   // (2,)
                 const float* __restrict__ b2,   // (16,)
                 const float* __restrict__ fb1,  // (64,)
                 const float* __restrict__ fw2,  // (2,64)
                 const float* __restrict__ fb2,  // (2,)
                 const float* __restrict__ fw3,  // (1,1)
                 const float* __restrict__ fb3,  // (1,)
                 const float* __restrict__ qp,   // (8,)
                 const unsigned short* __restrict__ ws,
                 float* __restrict__ out)        // (B,2)
{
    __shared__ __align__(16) unsigned int p1u[16 * P1_S];  // 19200 B
    __shared__ __align__(16) float zbuf[4 * 32];           //   512 B

    const int t = threadIdx.x;
    const int wv = t >> 6;
    const int lane = t & 63;
    const int n = lane & 15;
    const int q = lane >> 4;
    const long base = (long)blockIdx.x * 16;
    unsigned short* hb16 = (unsigned short*)p1u;   // u16 view for hi/lo planes

    // zero own wave's samples' pad cols 288..295 (read by conv2 dead k-groups)
    if (lane < 32)
        p1u[(4 * wv + (lane >> 3)) * P1_S + 288 + (lane & 7)] = 0u;

    // ---- conv1 + relu + pool: wave-local fp32 pk_fma, 3 items/lane ----
    {
        v2f w1p[25];
        #pragma unroll
        for (int k = 0; k < 25; ++k)
            w1p[k] = (v2f){w1[k], w1[25 + k]};          // wave-uniform -> SGPR pairs
        const v2f bias1 = (v2f){b1[0], b1[1]};

        #pragma unroll
        for (int it = 0; it < 3; ++it) {
            int idx = it * 64 + lane;                    // [0,192) within wave
            int sl = idx / 48;                           // local sample 0..3
            int r = idx - sl * 48;
            int i = r >> 2, jh = r & 3;
            const int s = 4 * wv + sl;                   // wave-exclusive sample
            const float* xrow = x + (base + s) * 784;
            v2f acc[12];
            #pragma unroll
            for (int qq = 0; qq < 12; ++qq) acc[qq] = (v2f){0.f, 0.f};
            #pragma unroll
            for (int u = 0; u < 6; ++u) {
                const v2f* xp = (const v2f*)(xrow + (2 * i + u) * 28 + 6 * jh);
                v2f P[5] = { xp[0], xp[1], xp[2], xp[3], xp[4] };
                #pragma unroll
                for (int a = 0; a < 2; ++a) {
                    if (a <= u && (u - a) <= 4) {
                        const int wu = u - a;
                        #pragma unroll
                        for (int v = 0; v < 5; ++v) {
                            #pragma unroll
                            for (int j = 0; j < 6; ++j) {
                                const int e = j + v;
                                if (e & 1) { PK_FMA_W1(acc[a * 6 + j], w1p[wu * 5 + v], P[e >> 1]); }
                                else       { PK_FMA_W0(acc[a * 6 + j], w1p[wu * 5 + v], P[e >> 1]); }
                            }
                        }
                    }
                }
            }
            #pragma unroll
            for (int m = 0; m < 3; ++m) {
                v2f mx = vmax2(vmax2(acc[2 * m], acc[2 * m + 1]),
                               vmax2(acc[6 + 2 * m], acc[7 + 2 * m]));
                mx = mx + bias1;
                mx = vmax2(mx, (v2f){0.f, 0.f});
                int pc = 3 * jh + m;
                int off = s * P1_S + i * 12 + pc;
                p1u[off] = pack1(mx.x);            // channel 0 plane
                p1u[off + 144] = pack1(mx.y);      // channel 1 plane
            }
        }
    }
    // Block barrier: ALSO a compiler scheduling-region boundary. Replacing it
    // with a wave-local lgkmcnt fence (r10/r11) fused conv1+conv2 regions and
    // spilled ~10 dwords/thread past the 64-VGPR cap (WRITE_SIZE 0.5->41 MB).
    __syncthreads();

    // ---- conv2 + relu + pool: transposed split-bf16 MFMA, reg pooling,
    //      pooled output -> u16 hi/lo planes inside the overlay region ----
    {
        const bf16x8* B2h = (const bf16x8*)(ws + A2_HI);
        const bf16x8* B2l = (const bf16x8*)(ws + A2_LO);
        bf16x8 b_h[3], b_l[3];
        #pragma unroll
        for (int cc = 0; cc < 3; ++cc) {
            b_h[cc] = B2h[cc * 64 + lane];
            b_l[cc] = B2l[cc * 64 + lane];
        }
        // A side: lane holds A[m = lane&15][k = q*8+j].
        //   m = quad*4 + di*2 + dj : conv_i = 2*tt+di, conv_j = 2*quad+dj
        //   k-group (cc*4+q) = kernel row ch*5+u, j = v  (5 contiguous dwords)
        const int quad = n >> 2;
        const int di = (n >> 1) & 1;
        const int dj = n & 1;
        const int scol = 2 * quad + dj;
        int chu[3];
        #pragma unroll
        for (int cc = 0; cc < 3; ++cc) {
            int row = cc * 4 + q;
            int ch = (row >= 5) ? 1 : 0;
            int u = row - 5 * ch;
            chu[cc] = (row < 10) ? (ch * 144 + u * 12) : -1;
        }
        const float bias = b2[n];           // oc = n

        for (int sp = 0; sp < 4; ++sp) {
            const int smp = 4 * wv + sp;    // wave-exclusive sample rows
            const int sbase = smp * P1_S;
            const int zaddr = sbase + 288;  // zeroed pad
            float pvv[4];
            __builtin_amdgcn_s_setprio(1);
            #pragma unroll
            for (int tt = 0; tt < 4; ++tt) {
                int pbase = sbase + (2 * tt + di) * 12 + scol;
                f32x4 acc = {0.f, 0.f, 0.f, 0.f};
                f32x4 acc2 = {0.f, 0.f, 0.f, 0.f};
                #pragma unroll
                for (int cc = 0; cc < 3; ++cc) {
                    int a = (chu[cc] >= 0) ? (pbase + chu[cc]) : zaddr;
                    unsigned int e0 = p1u[a],     e1 = p1u[a + 1], e2 = p1u[a + 2],
                                 e3 = p1u[a + 3], e4 = p1u[a + 4];
                    B8 AH, AL;
                    AH.u[0] = __builtin_amdgcn_perm(e1, e0, SEL_HI);
                    AH.u[1] = __builtin_amdgcn_perm(e3, e2, SEL_HI);
                    AH.u[2] = e4 >> 16;
                    AH.u[3] = 0u;
                    AL.u[0] = __builtin_amdgcn_perm(e1, e0, SEL_LO);
                    AL.u[1] = __builtin_amdgcn_perm(e3, e2, SEL_LO);
                    AL.u[2] = e4 & 0xFFFFu;
                    AL.u[3] = 0u;
                    acc  = MFMA16(AH.v, b_h[cc], acc);
                    acc2 = MFMA16(AL.v, b_h[cc], acc2);
                    acc  = MFMA16(AH.v, b_l[cc], acc);
                }
                acc = acc + acc2;
                // D row = q*4 + r : pool quad q, member r; col = n = oc.
                float pv = fmaxf(fmaxf(acc[0], acc[1]), fmaxf(acc[2], acc[3]));
                pvv[tt] = fmaxf(pv + bias, 0.f);
            }
            __builtin_amdgcn_s_setprio(0);
            // writeback to u16 planes: col k' = tt*64 + lane = (tt*4+q)*16 + n.
            // hi at u16 col k', lo at 256 + k' (both inside dword cols 0..255).
            #pragma unroll
            for (int tt = 0; tt < 4; ++tt) {
                unsigned int pu = __float_as_uint(pvv[tt]);
                unsigned int hi = pu & 0xFFFF0000u;
                float lo = pvv[tt] - __uint_as_float(hi);
                int col = tt * 64 + lane;
                hb16[smp * 600 + col] = (unsigned short)(pu >> 16);
                hb16[smp * 600 + 256 + col] = (unsigned short)(__float_as_uint(lo) >> 16);
            }
        }
    }
    __syncthreads();

    // ---- fc1 (split-bf16 MFMA, M=64, K=256, N=16 samples) + fc2 partials ----
    {
        const bf16x8* A1h = (const bf16x8*)(ws + A1_HI);
        const bf16x8* A1l = (const bf16x8*)(ws + A1_LO);
        const int abase = (wv * 16 + n) * 32 + q;    // A row m = wv*16+n
        const unsigned short* brow = hb16 + n * 600; // sample n's planes
        f32x4 acc = {0.f, 0.f, 0.f, 0.f};
        f32x4 acc2 = {0.f, 0.f, 0.f, 0.f};
        __builtin_amdgcn_s_setprio(1);
        #pragma unroll
        for (int kk = 0; kk < 8; ++kk) {
            bf16x8 ah = A1h[abase + kk * 4];
            bf16x8 al = A1l[abase + kk * 4];
            // B[k'=kk*32+q*8+j][n]: direct b128 reads, no perms
            bf16x8 bh = *(const bf16x8*)(brow + kk * 32 + q * 8);
            bf16x8 bl = *(const bf16x8*)(brow + 256 + kk * 32 + q * 8);
            acc  = MFMA16(ah, bh, acc);
            acc2 = MFMA16(ah, bl, acc2);
            acc  = MFMA16(al, bh, acc);
        }
        __builtin_amdgcn_s_setprio(0);
        acc = acc + acc2;
        // D rows m = wv*16 + q*4 + r, cols n = sample
        f32x4 fb4 = *(const f32x4*)(fb1 + wv * 16 + q * 4);
        f32x4 w20 = *(const f32x4*)(fw2 + wv * 16 + q * 4);
        f32x4 w21 = *(const f32x4*)(fw2 + 64 + wv * 16 + q * 4);
        float p0 = 0.f, p1v = 0.f;
        #pragma unroll
        for (int r = 0; r < 4; ++r) {
            float a = fmaxf(acc[r] + fb4[r], 0.f);
            p0  = fmaf(a, w20[r], p0);
            p1v = fmaf(a, w21[r], p1v);
        }
        p0  += __shfl_xor(p0, 16, 64);  p0  += __shfl_xor(p0, 32, 64);
        p1v += __shfl_xor(p1v, 16, 64); p1v += __shfl_xor(p1v, 32, 64);
        if (q == 0) {
            zbuf[wv * 32 + n * 2]     = p0;
            zbuf[wv * 32 + n * 2 + 1] = p1v;
        }
    }
    __syncthreads();
    if (wv != 0) return;          // tail on wave 0 only

    // ---- fc2 sum + quantum + fc3 + log_softmax (wave 0, 16 samples) ----
    {
        int s = lane & 15;
        float x0 = fb2[0] + zbuf[s * 2]     + zbuf[32 + s * 2]
                          + zbuf[64 + s * 2] + zbuf[96 + s * 2];
        float x1 = fb2[1] + zbuf[s * 2 + 1] + zbuf[32 + s * 2 + 1]
                          + zbuf[64 + s * 2 + 1] + zbuf[96 + s * 2 + 1];

        float sr[4], si[4];
        {
            float th0 = -x0 - x1, th1 = -x0 + x1, th2 = x0 - x1, th3 = x0 + x1;
            sr[0] = 0.5f * __cosf(th0); si[0] = 0.5f * __sinf(th0);
            sr[1] = 0.5f * __cosf(th1); si[1] = 0.5f * __sinf(th1);
            sr[2] = 0.5f * __cosf(th2); si[2] = 0.5f * __sinf(th2);
            sr[3] = 0.5f * __cosf(th3); si[3] = 0.5f * __sinf(th3);
        }
        {
            float tr = sr[2]; sr[2] = sr[3]; sr[3] = tr;
            float ti = si[2]; si[2] = si[3]; si[3] = ti;
            float ang = ((float)M_PI - x0) * ((float)M_PI - x1);
            float ca = __cosf(ang), sa = __sinf(ang);
            float r, im;
            r = sr[0]; im = si[0]; sr[0] = r*ca + im*sa; si[0] = im*ca - r*sa;
            r = sr[2]; im = si[2]; sr[2] = r*ca + im*sa; si[2] = im*ca - r*sa;
            r = sr[1]; im = si[1]; sr[1] = r*ca - im*sa; si[1] = im*ca + r*sa;
            r = sr[3]; im = si[3]; sr[3] = r*ca - im*sa; si[3] = im*ca + r*sa;
            tr = sr[2]; sr[2] = sr[3]; sr[3] = tr;
            ti = si[2]; si[2] = si[3]; si[3] = ti;
        }
        float cp[8], sp[8];
        #pragma unroll
        for (int g = 0; g < 8; ++g) { float qv = qp[g]; cp[g] = __cosf(qv); sp[g] = __sinf(qv); }

        #define QRY0(cc, ss) { \
            float a0r=sr[0], a0i=si[0], a1r=sr[2], a1i=si[2]; \
            sr[0]=cc*a0r-ss*a1r; si[0]=cc*a0i-ss*a1i; \
            sr[2]=ss*a0r+cc*a1r; si[2]=ss*a0i+cc*a1i; \
            float b0r=sr[1], b0i=si[1], b1r=sr[3], b1i=si[3]; \
            sr[1]=cc*b0r-ss*b1r; si[1]=cc*b0i-ss*b1i; \
            sr[3]=ss*b0r+cc*b1r; si[3]=ss*b0i+cc*b1i; }
        #define QRY1(cc, ss) { \
            float a0r=sr[0], a0i=si[0], a1r=sr[1], a1i=si[1]; \
            sr[0]=cc*a0r-ss*a1r; si[0]=cc*a0i-ss*a1i; \
            sr[1]=ss*a0r+cc*a1r; si[1]=ss*a0i+cc*a1i; \
            float b0r=sr[2], b0i=si[2], b1r=sr[3], b1i=si[3]; \
            sr[2]=cc*b0r-ss*b1r; si[2]=cc*b0i-ss*b1i; \
            sr[3]=ss*b0r+cc*b1r; si[3]=ss*b0i+cc*b1i; }
        #define QSWAP(i_, j_) { float tr=sr[i_]; sr[i_]=sr[j_]; sr[j_]=tr; \
                                float ti=si[i_]; si[i_]=si[j_]; si[j_]=ti; }

        QRY0(cp[0], sp[0]);
        QRY1(cp[1], sp[1]);
        QSWAP(2, 3);                 // cnot01
        QRY0(cp[2], sp[2]);
        QRY1(cp[3], sp[3]);
        QSWAP(1, 3);                 // cnot10
        QRY0(cp[4], sp[4]);
        QRY1(cp[5], sp[5]);
        QSWAP(2, 3);                 // cnot01
        QRY0(cp[6], sp[6]);
        QRY1(cp[7], sp[7]);

        float qv = (sr[0]*sr[0] + si[0]*si[0])
                 - (sr[1]*sr[1] + si[1]*si[1])
                 - (sr[2]*sr[2] + si[2]*si[2])
                 + (sr[3]*sr[3] + si[3]*si[3]);
        float y = fmaf(qv, fw3[0], fb3[0]);
        float l0 = y, l1 = 1.0f - y;
        float m = fmaxf(l0, l1);
        float lse = m + __logf(__expf(l0 - m) + __expf(l1 - m));
        if (lane < 32) {
            int comp = lane >> 4;
            out[(base + s) * 2 + comp] = comp ? (l1 - lse) : (l0 - lse);
        }
        #undef QRY0
        #undef QRY1
        #undef QSWAP
    }
}

extern "C" void kernel_launch(void* const* d_in, const int* in_sizes, int n_in,
                              void* d_out, int out_size, void* d_ws, size_t ws_size,
                              hipStream_t stream) {
    const float* x   = (const float*)d_in[0];
    const float* w1  = (const float*)d_in[1];
    const float* b1  = (const float*)d_in[2];
    const float* w2  = (const float*)d_in[3];
    const float* b2  = (const float*)d_in[4];
    const float* fw1 = (const float*)d_in[5];
    const float* fb1 = (const float*)d_in[6];
    const float* fw2 = (const float*)d_in[7];
    const float* fb2 = (const float*)d_in[8];
    const float* fw3 = (const float*)d_in[9];
    const float* fb3 = (const float*)d_in[10];
    const float* qp  = (const float*)d_in[11];
    float* outp = (float*)d_out;
    unsigned short* wsp = (unsigned short*)d_ws;

    hipLaunchKernelGGL(hqcnn_prep, dim3(64), dim3(256), 0, stream, w2, fw1, wsp);

    int B = in_sizes[0] / 784;     // 65536
    int nblk = B / 16;             // 16 samples per block
    hipLaunchKernelGGL(hqcnn_fused, dim3(nblk), dim3(256), 0, stream,
                       x, w1, b1, b2, fb1, fw2, fb2, fw3, fb3, qp, wsp, outp);
}

// Round 8
// 370.265 us; speedup vs baseline: 1.0910x; 1.0353x over previous
//
#include <hip/hip_runtime.h>
#include <math.h>

// Fused HQCNN, round 13: EXACT round-9 structure (best measured: 153 us,
// WRITE=512KB, no spill) + ONE change: hi/lo PLANE storage for conv2's pooled
// output. fc1 B-frags become two aligned ds_read_b128 (hi plane, lo plane) --
// all 64 fc1 v_perm_b32/thread deleted; conv2 writeback pays 2x ds_write_b16
// per value instead of 1x b32.
// Reverted from r12: setprio (m190: negative in barrier-locked kernels),
// wave-local conv1 mapping (confounded with residual 8MB spill).
// - conv1: block-distributed, 768 items / 256 threads = 3 each, r9 body.
// - conv2: transposed split-bf16 MFMA, reg-local pooling, wave-exclusive
//   sample rows, output overlaid into p1u as u16 planes (hi: cols 0..255,
//   lo: 256..511; k' = s16*16+oc).
// - fc1: M=64 K=256 N=16, A prepped in d_ws (k'-permuted), B direct b128.
// - wave-0 tail; 16 samples/block; 19.7 KB LDS -> 8 blocks/CU.

typedef float v2f __attribute__((ext_vector_type(2)));
typedef float f32x4 __attribute__((ext_vector_type(4)));
typedef short bf16x8 __attribute__((ext_vector_type(8)));

union B8 { unsigned int u[4]; bf16x8 v; };

static __device__ __forceinline__ v2f vmax2(v2f a, v2f b) {
    return __builtin_elementwise_max(a, b);
}

// acc = w * splat(x.word) + acc ; w wave-uniform (SGPR pair), x v2f.
#define PK_FMA_W0(acc, w, xp) \
    asm("v_pk_fma_f32 %0, %1, %2, %0 op_sel:[0,0,0] op_sel_hi:[1,0,1]" \
        : "+v"(acc) : "s"(w), "v"(xp))
#define PK_FMA_W1(acc, w, xp) \
    asm("v_pk_fma_f32 %0, %1, %2, %0 op_sel:[0,1,0] op_sel_hi:[1,1,1]" \
        : "+v"(acc) : "s"(w), "v"(xp))

#define MFMA16(a, b, c) __builtin_amdgcn_mfma_f32_16x16x32_bf16(a, b, c, 0, 0, 0)

// byte selectors for v_perm_b32(hiSrc, loSrc, sel)
#define SEL_HI 0x07060302u   // take high16 of each source dword
#define SEL_LO 0x05040100u   // take low16 of each source dword

// pack float -> [hi-bf16 | lo-bf16] dword (truncation split)
static __device__ __forceinline__ unsigned int pack1(float v) {
    unsigned int hi = __float_as_uint(v) & 0xFFFF0000u;
    float lo = v - __uint_as_float(hi);
    return hi | (__float_as_uint(lo) >> 16);
}

// ws layout (ushort units)
#define A2_HI 0
#define A2_LO 1536
#define A1_HI 3072
#define A1_LO (3072 + 16384)
// total 35840 ushorts = 71680 B

#define P1_S 300   // dwords per sample: 288 data (2 ch x 144) + 8 zero pad.
                   // After conv2: u16 cols 0..255 = hi plane, 256..511 = lo
                   // plane of the pooled output (k' = s16*16+oc).

__global__ __launch_bounds__(256)
void hqcnn_prep(const float* __restrict__ w2, const float* __restrict__ fw1,
                unsigned short* __restrict__ ws) {
    int t = blockIdx.x * 256 + threadIdx.x;
    if (blockIdx.x == 0) {
        // conv2 B-frags, frag-lane order: ws[cc*512 + lane*8 + j] holds
        // B[k=(lane>>4)*8+j][n=lane&15] ; k-group (cc*4+q) = row ch*5+u, j = v
        for (int e = threadIdx.x; e < 1536; e += 256) {
            int cc = e >> 9, r = e & 511;
            int lid = r >> 3, j = r & 7;
            int nn = lid & 15, qq = lid >> 4;
            int row = cc * 4 + qq;
            int ch = (row >= 5) ? 1 : 0;
            int u = row - 5 * ch;
            float val = (row < 10 && j < 5) ? w2[nn * 50 + ch * 25 + u * 5 + j] : 0.f;
            unsigned int uu = __float_as_uint(val);
            float lo = val - __uint_as_float(uu & 0xFFFF0000u);
            ws[A2_HI + e] = (unsigned short)(uu >> 16);
            ws[A2_LO + e] = (unsigned short)(__float_as_uint(lo) >> 16);
        }
    }
    // fc1 A with K permuted: k' = s16*16 + oc  <->  orig k = oc*16 + s16
    for (int e = t; e < 16384; e += gridDim.x * 256) {
        int m = e >> 8, kp = e & 255;
        int oc = kp & 15, s16 = kp >> 4;
        float val = fw1[m * 256 + oc * 16 + s16];
        unsigned int u = __float_as_uint(val);
        float lo = val - __uint_as_float(u & 0xFFFF0000u);
        ws[A1_HI + e] = (unsigned short)(u >> 16);
        ws[A1_LO + e] = (unsigned short)(__float_as_uint(lo) >> 16);
    }
}

__global__ __launch_bounds__(256, 8)
void hqcnn_fused(const float* __restrict__ x,    // (B,1,28,28)
                 const float* __restrict__ w1,   // (2,1,5,5)
                 const float* __restrict__ b1,   // (2,)
                 const float* __restrict__ b2,   // (16,)
                 const float* __restrict__ fb1,  // (64,)
                 const float* __restrict__ fw2,  // (2,64)
                 const float* __restrict__ fb2,  // (2,)
                 const float* __restrict__ fw3,  // (1,1)
                 const float* __restrict__ fb3,  // (1,)
                 const float* __restrict__ qp,   // (8,)
                 const unsigned short* __restrict__ ws,
                 float* __restrict__ out)        // (B,2)
{
    __shared__ __align__(16) unsigned int p1u[16 * P1_S];  // 19200 B
    __shared__ __align__(16) float zbuf[4 * 32];           //   512 B

    const int t = threadIdx.x;
    const int wv = t >> 6;
    const int lane = t & 63;
    const int n = lane & 15;
    const int q = lane >> 4;
    const long base = (long)blockIdx.x * 16;
    unsigned short* hb16 = (unsigned short*)p1u;   // u16 view for hi/lo planes

    // zero the per-sample pad cols 288..295 (read by conv2's dead k-groups)
    if (t < 128)
        p1u[(t >> 3) * P1_S + 288 + (t & 7)] = 0u;

    // ---- conv1 + relu + pool: block-distributed fp32 pk_fma, 3 items/thread ----
    {
        v2f w1p[25];
        #pragma unroll
        for (int k = 0; k < 25; ++k)
            w1p[k] = (v2f){w1[k], w1[25 + k]};          // wave-uniform -> SGPR pairs
        const v2f bias1 = (v2f){b1[0], b1[1]};

        #pragma unroll
        for (int it = 0; it < 3; ++it) {
            int f = t + it * 256;                        // 768 = 16 samples x 48 items
            int s = f / 48;
            int r = f - s * 48;
            int i = r >> 2, jh = r & 3;
            const float* xrow = x + (base + s) * 784;
            v2f acc[12];
            #pragma unroll
            for (int qq = 0; qq < 12; ++qq) acc[qq] = (v2f){0.f, 0.f};
            #pragma unroll
            for (int u = 0; u < 6; ++u) {
                const v2f* xp = (const v2f*)(xrow + (2 * i + u) * 28 + 6 * jh);
                v2f P[5] = { xp[0], xp[1], xp[2], xp[3], xp[4] };
                #pragma unroll
                for (int a = 0; a < 2; ++a) {
                    if (a <= u && (u - a) <= 4) {
                        const int wu = u - a;
                        #pragma unroll
                        for (int v = 0; v < 5; ++v) {
                            #pragma unroll
                            for (int j = 0; j < 6; ++j) {
                                const int e = j + v;
                                if (e & 1) { PK_FMA_W1(acc[a * 6 + j], w1p[wu * 5 + v], P[e >> 1]); }
                                else       { PK_FMA_W0(acc[a * 6 + j], w1p[wu * 5 + v], P[e >> 1]); }
                            }
                        }
                    }
                }
            }
            #pragma unroll
            for (int m = 0; m < 3; ++m) {
                v2f mx = vmax2(vmax2(acc[2 * m], acc[2 * m + 1]),
                               vmax2(acc[6 + 2 * m], acc[7 + 2 * m]));
                mx = mx + bias1;
                mx = vmax2(mx, (v2f){0.f, 0.f});
                int pc = 3 * jh + m;
                int off = s * P1_S + i * 12 + pc;
                p1u[off] = pack1(mx.x);            // channel 0 plane
                p1u[off + 144] = pack1(mx.y);      // channel 1 plane
            }
        }
    }
    __syncthreads();

    // ---- conv2 + relu + pool: transposed split-bf16 MFMA, reg pooling,
    //      pooled output -> u16 hi/lo planes inside the overlay region ----
    {
        const bf16x8* B2h = (const bf16x8*)(ws + A2_HI);
        const bf16x8* B2l = (const bf16x8*)(ws + A2_LO);
        bf16x8 b_h[3], b_l[3];
        #pragma unroll
        for (int cc = 0; cc < 3; ++cc) {
            b_h[cc] = B2h[cc * 64 + lane];
            b_l[cc] = B2l[cc * 64 + lane];
        }
        // A side: lane holds A[m = lane&15][k = q*8+j].
        //   m = quad*4 + di*2 + dj : conv_i = 2*tt+di, conv_j = 2*quad+dj
        //   k-group (cc*4+q) = kernel row ch*5+u, j = v  (5 contiguous dwords)
        const int quad = n >> 2;
        const int di = (n >> 1) & 1;
        const int dj = n & 1;
        const int scol = 2 * quad + dj;
        int chu[3];
        #pragma unroll
        for (int cc = 0; cc < 3; ++cc) {
            int row = cc * 4 + q;
            int ch = (row >= 5) ? 1 : 0;
            int u = row - 5 * ch;
            chu[cc] = (row < 10) ? (ch * 144 + u * 12) : -1;
        }
        const float bias = b2[n];           // oc = n

        for (int sp = 0; sp < 4; ++sp) {
            const int smp = 4 * wv + sp;    // wave-exclusive sample rows
            const int sbase = smp * P1_S;
            const int zaddr = sbase + 288;  // zeroed pad
            float pvv[4];
            #pragma unroll
            for (int tt = 0; tt < 4; ++tt) {
                int pbase = sbase + (2 * tt + di) * 12 + scol;
                f32x4 acc = {0.f, 0.f, 0.f, 0.f};
                f32x4 acc2 = {0.f, 0.f, 0.f, 0.f};
                #pragma unroll
                for (int cc = 0; cc < 3; ++cc) {
                    int a = (chu[cc] >= 0) ? (pbase + chu[cc]) : zaddr;
                    unsigned int e0 = p1u[a],     e1 = p1u[a + 1], e2 = p1u[a + 2],
                                 e3 = p1u[a + 3], e4 = p1u[a + 4];
                    B8 AH, AL;
                    AH.u[0] = __builtin_amdgcn_perm(e1, e0, SEL_HI);
                    AH.u[1] = __builtin_amdgcn_perm(e3, e2, SEL_HI);
                    AH.u[2] = e4 >> 16;
                    AH.u[3] = 0u;
                    AL.u[0] = __builtin_amdgcn_perm(e1, e0, SEL_LO);
                    AL.u[1] = __builtin_amdgcn_perm(e3, e2, SEL_LO);
                    AL.u[2] = e4 & 0xFFFFu;
                    AL.u[3] = 0u;
                    acc  = MFMA16(AH.v, b_h[cc], acc);
                    acc2 = MFMA16(AL.v, b_h[cc], acc2);
                    acc  = MFMA16(AH.v, b_l[cc], acc);
                }
                acc = acc + acc2;
                // D row = q*4 + r : pool quad q, member r; col = n = oc.
                float pv = fmaxf(fmaxf(acc[0], acc[1]), fmaxf(acc[2], acc[3]));
                pvv[tt] = fmaxf(pv + bias, 0.f);
            }
            // writeback to u16 planes: col k' = tt*64 + lane = (tt*4+q)*16 + n.
            // hi at u16 col k', lo at 256 + k' (both inside dword cols 0..255).
            // Data-dependent on all reads of this sample -> naturally ordered.
            #pragma unroll
            for (int tt = 0; tt < 4; ++tt) {
                unsigned int pu = __float_as_uint(pvv[tt]);
                unsigned int hi = pu & 0xFFFF0000u;
                float lo = pvv[tt] - __uint_as_float(hi);
                int col = tt * 64 + lane;
                hb16[smp * 600 + col] = (unsigned short)(pu >> 16);
                hb16[smp * 600 + 256 + col] = (unsigned short)(__float_as_uint(lo) >> 16);
            }
        }
    }
    __syncthreads();

    // ---- fc1 (split-bf16 MFMA, M=64, K=256, N=16 samples) + fc2 partials ----
    {
        const bf16x8* A1h = (const bf16x8*)(ws + A1_HI);
        const bf16x8* A1l = (const bf16x8*)(ws + A1_LO);
        const int abase = (wv * 16 + n) * 32 + q;    // A row m = wv*16+n
        const unsigned short* brow = hb16 + n * 600; // sample n's planes
        f32x4 acc = {0.f, 0.f, 0.f, 0.f};
        f32x4 acc2 = {0.f, 0.f, 0.f, 0.f};
        #pragma unroll
        for (int kk = 0; kk < 8; ++kk) {
            bf16x8 ah = A1h[abase + kk * 4];
            bf16x8 al = A1l[abase + kk * 4];
            // B[k'=kk*32+q*8+j][n]: direct b128 reads, no perms
            bf16x8 bh = *(const bf16x8*)(brow + kk * 32 + q * 8);
            bf16x8 bl = *(const bf16x8*)(brow + 256 + kk * 32 + q * 8);
            acc  = MFMA16(ah, bh, acc);
            acc2 = MFMA16(ah, bl, acc2);
            acc  = MFMA16(al, bh, acc);
        }
        acc = acc + acc2;
        // D rows m = wv*16 + q*4 + r, cols n = sample
        f32x4 fb4 = *(const f32x4*)(fb1 + wv * 16 + q * 4);
        f32x4 w20 = *(const f32x4*)(fw2 + wv * 16 + q * 4);
        f32x4 w21 = *(const f32x4*)(fw2 + 64 + wv * 16 + q * 4);
        float p0 = 0.f, p1v = 0.f;
        #pragma unroll
        for (int r = 0; r < 4; ++r) {
            float a = fmaxf(acc[r] + fb4[r], 0.f);
            p0  = fmaf(a, w20[r], p0);
            p1v = fmaf(a, w21[r], p1v);
        }
        p0  += __shfl_xor(p0, 16, 64);  p0  += __shfl_xor(p0, 32, 64);
        p1v += __shfl_xor(p1v, 16, 64); p1v += __shfl_xor(p1v, 32, 64);
        if (q == 0) {
            zbuf[wv * 32 + n * 2]     = p0;
            zbuf[wv * 32 + n * 2 + 1] = p1v;
        }
    }
    __syncthreads();
    if (wv != 0) return;          // tail on wave 0 only

    // ---- fc2 sum + quantum + fc3 + log_softmax (wave 0, 16 samples) ----
    {
        int s = lane & 15;
        float x0 = fb2[0] + zbuf[s * 2]     + zbuf[32 + s * 2]
                          + zbuf[64 + s * 2] + zbuf[96 + s * 2];
        float x1 = fb2[1] + zbuf[s * 2 + 1] + zbuf[32 + s * 2 + 1]
                          + zbuf[64 + s * 2 + 1] + zbuf[96 + s * 2 + 1];

        float sr[4], si[4];
        {
            float th0 = -x0 - x1, th1 = -x0 + x1, th2 = x0 - x1, th3 = x0 + x1;
            sr[0] = 0.5f * __cosf(th0); si[0] = 0.5f * __sinf(th0);
            sr[1] = 0.5f * __cosf(th1); si[1] = 0.5f * __sinf(th1);
            sr[2] = 0.5f * __cosf(th2); si[2] = 0.5f * __sinf(th2);
            sr[3] = 0.5f * __cosf(th3); si[3] = 0.5f * __sinf(th3);
        }
        {
            float tr = sr[2]; sr[2] = sr[3]; sr[3] = tr;
            float ti = si[2]; si[2] = si[3]; si[3] = ti;
            float ang = ((float)M_PI - x0) * ((float)M_PI - x1);
            float ca = __cosf(ang), sa = __sinf(ang);
            float r, im;
            r = sr[0]; im = si[0]; sr[0] = r*ca + im*sa; si[0] = im*ca - r*sa;
            r = sr[2]; im = si[2]; sr[2] = r*ca + im*sa; si[2] = im*ca - r*sa;
            r = sr[1]; im = si[1]; sr[1] = r*ca - im*sa; si[1] = im*ca + r*sa;
            r = sr[3]; im = si[3]; sr[3] = r*ca - im*sa; si[3] = im*ca + r*sa;
            tr = sr[2]; sr[2] = sr[3]; sr[3] = tr;
            ti = si[2]; si[2] = si[3]; si[3] = ti;
        }
        float cp[8], sp[8];
        #pragma unroll
        for (int g = 0; g < 8; ++g) { float qv = qp[g]; cp[g] = __cosf(qv); sp[g] = __sinf(qv); }

        #define QRY0(cc, ss) { \
            float a0r=sr[0], a0i=si[0], a1r=sr[2], a1i=si[2]; \
            sr[0]=cc*a0r-ss*a1r; si[0]=cc*a0i-ss*a1i; \
            sr[2]=ss*a0r+cc*a1r; si[2]=ss*a0i+cc*a1i; \
            float b0r=sr[1], b0i=si[1], b1r=sr[3], b1i=si[3]; \
            sr[1]=cc*b0r-ss*b1r; si[1]=cc*b0i-ss*b1i; \
            sr[3]=ss*b0r+cc*b1r; si[3]=ss*b0i+cc*b1i; }
        #define QRY1(cc, ss) { \
            float a0r=sr[0], a0i=si[0], a1r=sr[1], a1i=si[1]; \
            sr[0]=cc*a0r-ss*a1r; si[0]=cc*a0i-ss*a1i; \
            sr[1]=ss*a0r+cc*a1r; si[1]=ss*a0i+cc*a1i; \
            float b0r=sr[2], b0i=si[2], b1r=sr[3], b1i=si[3]; \
            sr[2]=cc*b0r-ss*b1r; si[2]=cc*b0i-ss*b1i; \
            sr[3]=ss*b0r+cc*b1r; si[3]=ss*b0i+cc*b1i; }
        #define QSWAP(i_, j_) { float tr=sr[i_]; sr[i_]=sr[j_]; sr[j_]=tr; \
                                float ti=si[i_]; si[i_]=si[j_]; si[j_]=ti; }

        QRY0(cp[0], sp[0]);
        QRY1(cp[1], sp[1]);
        QSWAP(2, 3);                 // cnot01
        QRY0(cp[2], sp[2]);
        QRY1(cp[3], sp[3]);
        QSWAP(1, 3);                 // cnot10
        QRY0(cp[4], sp[4]);
        QRY1(cp[5], sp[5]);
        QSWAP(2, 3);                 // cnot01
        QRY0(cp[6], sp[6]);
        QRY1(cp[7], sp[7]);

        float qv = (sr[0]*sr[0] + si[0]*si[0])
                 - (sr[1]*sr[1] + si[1]*si[1])
                 - (sr[2]*sr[2] + si[2]*si[2])
                 + (sr[3]*sr[3] + si[3]*si[3]);
        float y = fmaf(qv, fw3[0], fb3[0]);
        float l0 = y, l1 = 1.0f - y;
        float m = fmaxf(l0, l1);
        float lse = m + __logf(__expf(l0 - m) + __expf(l1 - m));
        if (lane < 32) {
            int comp = lane >> 4;
            out[(base + s) * 2 + comp] = comp ? (l1 - lse) : (l0 - lse);
        }
        #undef QRY0
        #undef QRY1
        #undef QSWAP
    }
}

extern "C" void kernel_launch(void* const* d_in, const int* in_sizes, int n_in,
                              void* d_out, int out_size, void* d_ws, size_t ws_size,
                              hipStream_t stream) {
    const float* x   = (const float*)d_in[0];
    const float* w1  = (const float*)d_in[1];
    const float* b1  = (const float*)d_in[2];
    const float* w2  = (const float*)d_in[3];
    const float* b2  = (const float*)d_in[4];
    const float* fw1 = (const float*)d_in[5];
    const float* fb1 = (const float*)d_in[6];
    const float* fw2 = (const float*)d_in[7];
    const float* fb2 = (const float*)d_in[8];
    const float* fw3 = (const float*)d_in[9];
    const float* fb3 = (const float*)d_in[10];
    const float* qp  = (const float*)d_in[11];
    float* outp = (float*)d_out;
    unsigned short* wsp = (unsigned short*)d_ws;

    hipLaunchKernelGGL(hqcnn_prep, dim3(64), dim3(256), 0, stream, w2, fw1, wsp);

    int B = in_sizes[0] / 784;     // 65536
    int nblk = B / 16;             // 16 samples per block
    hipLaunchKernelGGL(hqcnn_fused, dim3(nblk), dim3(256), 0, stream,
                       x, w1, b1, b2, fb1, fw2, fb2, fw3, fb3, qp, wsp, outp);
}